// Round 16
// baseline (125.256 us; speedup 1.0000x reference)
//
#include <hip/hip_runtime.h>
#include <hip/hip_bf16.h>
#include <math.h>

// Cart2Polar: output[b,c,y,x] = bilinear_sample(grid_feat[b,c], gx(y,x), gy(y,x))
// ref_feat is fully overwritten by the reference's scatter -> unused.
// Shapes (fixed): grid_feat [4,64,480,480] f32, out [4,64,480,360] f32.
//
// R16 = R15 with the two half-tile gather clusters MERGED: all 32 dwordx2
// issue back-to-back, then counted drain (A while B still flies). R15's
// regression vs R13 (124.9 vs 118.9) was the serialized halves: full
// vmcnt(0) drain between clusters = 2 latency exposures, MLP halved.
// Keeps R15's full-128B-line nt stores (WRITE 230->187 MB confirmed).

#define BB 4
#define CC 64
#define HC 480
#define WC 480
#define HP 480
#define WP 360

#define TY 16
#define TX 32
#define BYT (HP / TY)                  // 30
#define BXT ((WP + TX - 1) / TX)       // 12 (xt=11 half-valid: computed, masked store)
#define CSPLIT 8
#define CCB (CC / CSPLIT)              // 8 channels per block
#define NWG (BB * BYT * BXT * CSPLIT)  // 11520
#define CB 8                           // = CCB, single LDS batch

typedef float f2a __attribute__((ext_vector_type(2), aligned(8)));

__global__ __launch_bounds__(256, 2) void c2p_kernel(const float* __restrict__ g,
                                                     float* __restrict__ out) {
    __shared__ float lds[CB][TY][TX + 1];   // [8][16][33]

    // identity mapping: round-robin over XCDs mixes radii (load balance, R8 win)
    const int logical = blockIdx.x;
    const int h  = logical & (CSPLIT - 1);
    const int t1 = logical >> 3;
    const int xt = t1 % BXT;
    const int t2 = t1 / BXT;
    const int yt = t2 % BYT;
    const int b  = t2 / BYT;

    const int tid  = threadIdx.x;
    const int lane = tid & 63;
    const int w    = tid >> 6;
    // gather mapping (both halves): wave = 16 consecutive y x 4 consecutive x
    const int ly  = lane >> 2;                // 0..15
    const int lxA = (w << 2) | (lane & 3);    // 0..15 (half A); half B = +16
    const int y   = yt * TY + ly;
    const int xA  = xt * TX + lxA;            // tail tile: theta wraps, sample
                                              // stays in disk -> in-bounds reads

    // polar grid math (matches reference, fp32)
    const float PI = 3.14159265358979323846f;
    float theta = PI - (float)xA * (2.0f * PI / (float)WP);
    float r = ((float)HP - 0.5f - (float)y + 3.0f) * (1.0f / ((float)HP + 3.0f)) * ((float)WC * 0.5f);
    float sn, cs;
    __sincosf(theta, &sn, &cs);
    // half B: theta_B = theta - 16*2pi/360; rotate (cs,sn) by constant angle
    const float cd = 0.96126169593831886f;    // cos(16*2pi/360)
    const float sd = 0.27563735581699916f;    // sin(16*2pi/360)
    const float csB = cs * cd + sn * sd;
    const float snB = sn * cd - cs * sd;

    const float scale = (float)(WC - 1) / (float)WC;
    const float half = (float)WC * 0.5f;

    constexpr int HWc = HC * WC;
    constexpr int HWp = HP * WP;
    const float* __restrict__ base = g + ((size_t)b * CC + h * CCB) * HWc;

    // per-half bilinear setup
    float gxA = (r * cs + half) * scale;
    float gyA = (r * sn + half) * scale;
    float gxB = (r * csB + half) * scale;
    float gyB = (r * snB + half) * scale;

    float x0fA = floorf(gxA), y0fA = floorf(gyA);
    float x0fB = floorf(gxB), y0fB = floorf(gyB);
    const float wx1A = gxA - x0fA, wy1A = gyA - y0fA;
    const float wx1B = gxB - x0fB, wy1B = gyB - y0fB;
    const float wx0A = 1.0f - wx1A, wy0A = 1.0f - wy1A;
    const float wx0B = 1.0f - wx1B, wy0B = 1.0f - wy1B;

    const float w00A = wx0A * wy0A, w10A = wx1A * wy0A;
    const float w01A = wx0A * wy1A, w11A = wx1A * wy1A;
    const float w00B = wx0B * wy0B, w10B = wx1B * wy0B;
    const float w01B = wx0B * wy1B, w11B = wx1B * wy1B;

    const int o0A = (int)y0fA * WC + (int)x0fA;   // in-bounds (proven geometry)
    const int o1A = o0A + WC;
    const int o0B = (int)y0fB * WC + (int)x0fB;
    const int o1B = o0B + WC;

    f2a a0A[CB], a1A[CB], a0B[CB], a1B[CB];

    // ---- merged cluster: 32 dwordx2 in flight (A loads 0..15, B loads 16..31) ----
#pragma unroll
    for (int j = 0; j < CB; ++j) {
        const float* p0 = base + (size_t)j * HWc + o0A;
        const float* p1 = base + (size_t)j * HWc + o1A;
        asm volatile("global_load_dwordx2 %0, %1, off" : "=v"(a0A[j]) : "v"(p0));
        asm volatile("global_load_dwordx2 %0, %1, off" : "=v"(a1A[j]) : "v"(p1));
    }
#pragma unroll
    for (int j = 0; j < CB; ++j) {
        const float* p0 = base + (size_t)j * HWc + o0B;
        const float* p1 = base + (size_t)j * HWc + o1B;
        asm volatile("global_load_dwordx2 %0, %1, off" : "=v"(a0B[j]) : "v"(p0));
        asm volatile("global_load_dwordx2 %0, %1, off" : "=v"(a1B[j]) : "v"(p1));
    }

    // ---- counted drain A: B's 16 loads remain in flight throughout ----
#pragma unroll
    for (int j = 0; j < CB; ++j) {
        asm volatile("s_waitcnt vmcnt(%0)" :: "i"(30 - 2 * j) : "memory");
        __builtin_amdgcn_sched_barrier(0);
        lds[j][ly][lxA] = a0A[j].x * w00A + a0A[j].y * w10A
                        + a1A[j].x * w01A + a1A[j].y * w11A;
    }
    // ---- counted drain B ----
#pragma unroll
    for (int j = 0; j < CB; ++j) {
        asm volatile("s_waitcnt vmcnt(%0)" :: "i"(14 - 2 * j) : "memory");
        __builtin_amdgcn_sched_barrier(0);
        lds[j][ly][lxA + 16] = a0B[j].x * w00B + a0B[j].y * w10B
                             + a1B[j].x * w01B + a1B[j].y * w11B;
    }
    __syncthreads();

    // ---- store phase: 2 rows x 32 cols per wave-instr = full 128B lines ----
    const int srow = tid >> 5;                // 0..7 (also srow+8)
    const int scol = tid & 31;                // 0..31
    const int sx = xt * TX + scol;
    const bool sok = (sx < WP);
    float* __restrict__ ob = out + ((size_t)b * CC + h * CCB) * HWp
                                 + (size_t)(yt * TY + srow) * WP + sx;
    if (sok) {
#pragma unroll
        for (int j = 0; j < CB; ++j) {
            __builtin_nontemporal_store(lds[j][srow][scol],     &ob[(size_t)j * HWp]);
            __builtin_nontemporal_store(lds[j][srow + 8][scol], &ob[(size_t)j * HWp + 8 * WP]);
        }
    }
}

extern "C" void kernel_launch(void* const* d_in, const int* in_sizes, int n_in,
                              void* d_out, int out_size, void* d_ws, size_t ws_size,
                              hipStream_t stream) {
    const float* grid_feat = (const float*)d_in[0];
    float* out = (float*)d_out;
    c2p_kernel<<<NWG, 256, 0, stream>>>(grid_feat, out);
}

// Round 17
// 119.170 us; speedup vs baseline: 1.0511x; 1.0511x over previous
//
#include <hip/hip_runtime.h>
#include <hip/hip_bf16.h>
#include <math.h>

// Cart2Polar: output[b,c,y,x] = bilinear_sample(grid_feat[b,c], gx(y,x), gy(y,x))
// ref_feat is fully overwritten by the reference's scatter -> unused.
// Shapes (fixed): grid_feat [4,64,480,480] f32, out [4,64,480,360] f32.
//
// R17 = exact R13 (session best: bench 118.9 us). Final structure and why:
//  - 16y x 4x wave gather footprint (R4: compact arc patch, 2.5x fewer
//    line-requests than x-major; the single biggest win after baseline)
//  - paired dwordx2 corner loads (R6: geometry proves no clamp/pad needed;
//    (x0,x0+1) contiguous -> 2 loads/channel instead of 4)
//  - asm-volatile gather cluster + counted vmcnt drain (R9/R10: forces
//    issue-order MLP; null vs compiler scheduling but keeps it deterministic)
//  - LDS-transposed 64B-row nt stores (R4 store coalescing; R14 A/B proved
//    nt >> plain at bench time: clean L2 for the gather working set)
//  - CSPLIT=8, 22080 blocks (R13: TLP/tail win, occupancy 86%)
//  - identity dispatch (R8: radius round-robin balances XCDs; R7/R11 proved
//    chunked locality swizzles lose to balance or are traffic-neutral)
// Residual wall (measured, 6 falsified attacks): per-CU vector-memory
// line-request throughput, ~28M L1-missing line-requests ~= 110-130 us.

#define BB 4
#define CC 64
#define HC 480
#define WC 480
#define HP 480
#define WP 360

#define TY 16
#define TX 16
#define BYT (HP / TY)                  // 30
#define BXT ((WP + TX - 1) / TX)       // 23 (last tile x>=360 lanes: computed, not stored)
#define CSPLIT 8
#define CCB (CC / CSPLIT)              // 8 channels per block
#define NWG (BB * BYT * BXT * CSPLIT)  // 22080
#define CB 8                           // = CCB, single LDS batch

typedef float f2a __attribute__((ext_vector_type(2), aligned(8)));

__global__ __launch_bounds__(256, 2) void c2p_kernel(const float* __restrict__ g,
                                                     float* __restrict__ out) {
    __shared__ float lds[CB][TY][TX + 1];   // +1 pad: conflict-free scalar r/w

    // identity mapping: round-robin over XCDs mixes radii (load balance, R8 win)
    const int logical = blockIdx.x;
    const int h  = logical & (CSPLIT - 1);
    const int t1 = logical >> 3;
    const int xt = t1 % BXT;
    const int t2 = t1 / BXT;
    const int yt = t2 % BYT;
    const int b  = t2 / BYT;

    const int tid  = threadIdx.x;
    const int lane = tid & 63;
    const int w    = tid >> 6;
    // gather-phase mapping: wave = 16 consecutive y (radii) x 4 consecutive x
    const int ly = lane >> 2;                 // 0..15
    const int lx = (w << 2) | (lane & 3);     // 0..15
    const int y  = yt * TY + ly;
    const int x  = xt * TX + lx;              // may be >=360 in last tile (not stored)

    // polar grid math (matches reference, fp32)
    const float PI = 3.14159265358979323846f;
    float theta = PI - (float)x * (2.0f * PI / (float)WP);
    float r = ((float)HP - 0.5f - (float)y + 3.0f) * (1.0f / ((float)HP + 3.0f)) * ((float)WC * 0.5f);
    float s, c;
    __sincosf(theta, &s, &c);
    float index_x = r * c + (float)WC * 0.5f;
    float index_y = r * s + (float)WC * 0.5f;
    const float scale = (float)(WC - 1) / (float)WC;
    float gx = index_x * scale;
    float gy = index_y * scale;

    float x0f = floorf(gx);
    float y0f = floorf(gy);
    float wx1 = gx - x0f;
    float wy1 = gy - y0f;
    float wx0 = 1.0f - wx1;
    float wy0 = 1.0f - wy1;

    // proven in-bounds for this geometry: x0,y0 in [0,478] -> no clamp/validity
    const int x0 = (int)x0f;
    const int y0 = (int)y0f;

    const float w00 = wx0 * wy0;
    const float w10 = wx1 * wy0;
    const float w01 = wx0 * wy1;
    const float w11 = wx1 * wy1;

    const int o0 = y0 * WC + x0;     // row y0, cols (x0, x0+1) as one float2
    const int o1 = o0 + WC;          // row y0+1

    constexpr int HWc = HC * WC;
    constexpr int HWp = HP * WP;

    const float* __restrict__ base = g + ((size_t)b * CC + h * CCB) * HWc;

    // store-phase mapping: x-major, 16 rows x 64B per wave-store
    const int srow = tid >> 4;                // 0..15
    const int scol = tid & 15;                // 0..15
    const int sy = yt * TY + srow;
    const int sx = xt * TX + scol;
    const bool sok = (sx < WP);
    float* __restrict__ ob = out + ((size_t)b * CC + h * CCB) * HWp + (size_t)sy * WP + sx;

    // ---- asm-forced gather cluster: 16 dwordx2 loads, all in flight ----
    f2a a0[CB], a1[CB];
#pragma unroll
    for (int j = 0; j < CB; ++j) {
        const float* p0 = base + (size_t)j * HWc + o0;
        const float* p1 = base + (size_t)j * HWc + o1;
        asm volatile("global_load_dwordx2 %0, %1, off"
                     : "=v"(a0[j]) : "v"(p0));
        asm volatile("global_load_dwordx2 %0, %1, off"
                     : "=v"(a1[j]) : "v"(p1));
    }

    // ---- counted drain: consume channel j while 2*(CB-1-j) loads still fly ----
#pragma unroll
    for (int j = 0; j < CB; ++j) {
        asm volatile("s_waitcnt vmcnt(%0)" :: "i"(2 * (CB - 1 - j)) : "memory");
        __builtin_amdgcn_sched_barrier(0);
        lds[j][ly][lx] = a0[j].x * w00 + a0[j].y * w10
                       + a1[j].x * w01 + a1[j].y * w11;
    }
    __syncthreads();

    if (sok) {
#pragma unroll
        for (int j = 0; j < CB; ++j)
            __builtin_nontemporal_store(lds[j][srow][scol], &ob[(size_t)j * HWp]);
    }
}

extern "C" void kernel_launch(void* const* d_in, const int* in_sizes, int n_in,
                              void* d_out, int out_size, void* d_ws, size_t ws_size,
                              hipStream_t stream) {
    const float* grid_feat = (const float*)d_in[0];
    float* out = (float*)d_out;
    c2p_kernel<<<NWG, 256, 0, stream>>>(grid_feat, out);
}